// Round 13
// baseline (240.370 us; speedup 1.0000x reference)
//
#include <hip/hip_runtime.h>
#include <hip/hip_bf16.h>

#define NN_ 1024

// ws ushort-element offsets (total ~11.8 MB of the 256 MiB ws)
#define U_WG   0         // 131072: Wg[j][k] 512x256 bf16  (k<128: W_ih, else W_hh) - native k-contiguous
#define U_WOUT 131072    // 16384:  WoutT[r][j] 128x128, j>=120 zero
#define U_SHI  147456    // 524288: bf16 hi of W_soc [e][8192]
#define U_SLO  671744    // 524288: bf16 lo residual
#define U_ACTH 1196032   // 262144: act_hi[n][k] 1024x256  (k: 0-63 emb, 64-127 pool, 128-255 h0)
#define U_ACTL 1458176   // 262144: act_lo residual
#define U_P    1720320   // 4194304: P[m][g*64+e] bf16

typedef __attribute__((ext_vector_type(8))) short short8;
typedef __attribute__((ext_vector_type(4))) float floatx4;

__device__ __forceinline__ float b2f_(unsigned short u) {
    return __uint_as_float(((unsigned)u) << 16);           // bf16 -> f32, exact
}
__device__ __forceinline__ unsigned short f2bu(float f) {  // f32 -> bf16 bits (RNE)
    __hip_bfloat16 b = __float2bfloat16(f);
    return *(unsigned short*)&b;
}
__device__ __forceinline__ float ldin(const void* p, int i, int isbf) {
    return isbf ? b2f_(((const unsigned short*)p)[i]) : ((const float*)p)[i];
}
__device__ __forceinline__ int detect_bf16(const void* Wih, int tid) {
    unsigned wv = ((const unsigned*)Wih)[tid];
    unsigned e8 = (wv >> 7) & 0xFFu;
    return (__syncthreads_count((e8 >= 96u && e8 <= 134u) ? 1 : 0) > 128) ? 1 : 0;
}

// ---- K0: one-time conversions: Wg bf16, WoutT bf16, W_soc hi/lo, h0 hi/lo -> act,
//          emb compute -> act. 868352 tasks over 262144 threads. ----
__global__ __launch_bounds__(256) void prep_kernel(
        const void* __restrict__ xoff, const void* __restrict__ h0,
        const void* __restrict__ Wsoc, const void* __restrict__ Wemb,
        const void* __restrict__ bemb, const void* __restrict__ Wih,
        const void* __restrict__ Whh,  const void* __restrict__ Wout,
        float* __restrict__ ws) {
    const int tid = threadIdx.x;
    const int isbf = detect_bf16(Wih, tid);
    unsigned short* u = (unsigned short*)ws;
    for (int t = blockIdx.x * 256 + tid; t < 868352; t += 262144) {
        if (t < 131072) {                          // Wg[j*256+k]
            int j = t >> 8, k = t & 255;
            float v = (k < 128) ? ldin(Wih, j * 128 + k, isbf)
                                : ldin(Whh, j * 128 + (k - 128), isbf);
            u[U_WG + t] = f2bu(v);
        } else if (t < 147456) {                   // WoutT[r*128+j]
            int t2 = t - 131072; int r = t2 >> 7, j = t2 & 127;
            u[U_WOUT + t2] = f2bu((j < 120) ? ldin(Wout, j * 128 + r, isbf) : 0.0f);
        } else if (t < 671744) {                   // W_soc split
            int t2 = t - 147456;
            float x = ldin(Wsoc, t2, isbf);
            unsigned short hi = f2bu(x);
            u[U_SHI + t2] = hi;
            u[U_SLO + t2] = f2bu(x - b2f_(hi));
        } else if (t < 802816) {                   // h0 split -> act k=128..255
            int t2 = t - 671744; int n = t2 >> 7, k = t2 & 127;
            float x = ldin(h0, t2, isbf);
            unsigned short hi = f2bu(x);
            u[U_ACTH + n * 256 + 128 + k] = hi;
            u[U_ACTL + n * 256 + 128 + k] = f2bu(x - b2f_(hi));
        } else {                                   // emb -> act k=0..63
            int t2 = t - 802816; int n = t2 >> 6, e = t2 & 63;
            float v = fmaf(ldin(xoff, 2 * n, isbf),     ldin(Wemb, 2 * e, isbf),
                      fmaf(ldin(xoff, 2 * n + 1, isbf), ldin(Wemb, 2 * e + 1, isbf),
                           ldin(bemb, e, isbf)));
            v = fmaxf(v, 0.0f);
            unsigned short hi = f2bu(v);
            u[U_ACTH + n * 256 + e] = hi;
            u[U_ACTL + n * 256 + e] = f2bu(v - b2f_(hi));
        }
    }
}

// ---- K1: P[m, g*64+e] = sum_h h0[m,h]*W_soc[e,g*128+h], hi/lo MFMA, pure loads ----
// Block = 16 m-rows x 256 cols (4 waves x 4 col-tiles). A from act(+128), B pre-split.
__global__ __launch_bounds__(256) void pgemm_kernel(float* __restrict__ ws) {
    const unsigned short* u = (const unsigned short*)ws;
    const short* Ah  = (const short*)(u + U_ACTH);
    const short* Al  = (const short*)(u + U_ACTL);
    const short* Shi = (const short*)(u + U_SHI);
    const short* Slo = (const short*)(u + U_SLO);
    unsigned short* P16 = (unsigned short*)ws + U_P;
    const int tid = threadIdx.x, lane = tid & 63, wv = tid >> 6;
    const int B_ = blockIdx.y * 64 + blockIdx.x;   // 0..1023
    const int mtile = B_ & 63, cgi = B_ >> 6;
    const int m = lane & 15, q = lane >> 4;
    const int abase = (mtile * 16 + m) * 256 + 128 + q * 8;   // h section of act
    short8 ah[4], al[4];
#pragma unroll
    for (int j = 0; j < 4; j++) {
        ah[j] = *(const short8*)(Ah + abase + 32 * j);
        al[j] = *(const short8*)(Al + abase + 32 * j);
    }
    const int rowl = mtile * 16 + q * 4;
#pragma unroll
    for (int t = 0; t < 4; t++) {
        const int n0 = cgi * 256 + wv * 64 + t * 16;
        const int nc = n0 + m;
        const int e = nc & 63, g = nc >> 6;
        const int wb = e * 8192 + g * 128 + q * 8;
        short8 bh[4], bl[4];
#pragma unroll
        for (int j = 0; j < 4; j++) {
            bh[j] = *(const short8*)(Shi + wb + 32 * j);
            bl[j] = *(const short8*)(Slo + wb + 32 * j);
        }
        floatx4 c = {0.0f, 0.0f, 0.0f, 0.0f};
#pragma unroll
        for (int j = 0; j < 4; j++) c = __builtin_amdgcn_mfma_f32_16x16x32_bf16(ah[j], bh[j], c, 0, 0, 0);
#pragma unroll
        for (int j = 0; j < 4; j++) c = __builtin_amdgcn_mfma_f32_16x16x32_bf16(ah[j], bl[j], c, 0, 0, 0);
#pragma unroll
        for (int j = 0; j < 4; j++) c = __builtin_amdgcn_mfma_f32_16x16x32_bf16(al[j], bh[j], c, 0, 0, 0);
#pragma unroll
        for (int r = 0; r < 4; r++)                // D: col=lane&15, row=q*4+r
            P16[(rowl + r) * 4096 + n0 + m] = f2bu(c[r]);
    }
}

// ---- K2: pool gather (2 agents/block), writes act k=64..127 hi/lo ----
__global__ __launch_bounds__(256) void pool_kernel(const void* __restrict__ xabs,
                                                   const void* __restrict__ b_soc,
                                                   const void* __restrict__ Wih_det,
                                                   float* __restrict__ ws) {
    __shared__ float xabs_s[2048];
    __shared__ int   off[2][NN_];
    __shared__ int   cnt_s[2];
    __shared__ float4 red4[2][8][16];
    const int tid = threadIdx.x;
    const int isbf = detect_bf16(Wih_det, tid);
    const int n0 = blockIdx.x * 2;
    unsigned short* u = (unsigned short*)ws;

    for (int i = tid; i < 2048; i += 256) xabs_s[i] = ldin(xabs, i, isbf);
    if (tid < 2) cnt_s[tid] = 0;
    __syncthreads();

    const int half = tid >> 7;                     // agent 0/1 (wave-uniform)
    const int t2 = tid & 127;
    const int n = n0 + half;
    {
        float xs = xabs_s[2 * n]     - 0.2f;       // x[n] - NS/2
        float ys = xabs_s[2 * n + 1] - 0.2f;
        for (int i = t2; i < NN_; i += 128) {
            float dx = xabs_s[2 * i]     - xs;
            float dy = xabs_s[2 * i + 1] - ys;
            int cx = (int)floorf(dx / 0.4f * 8.0f);
            int cy = (int)floorf(dy / 0.4f * 8.0f);
            bool valid = (dx >= 0.0f) && (dx < 0.4f) && (dy >= 0.0f) && (dy < 0.4f)
                      && (cx >= 0) && (cx < 8) && (cy >= 0) && (cy < 8) && (i != n);
            if (valid) {
                int idx = atomicAdd(&cnt_s[half], 1);
                off[half][idx] = i * 4096 + ((cy * 8 + cx) << 6);
            }
        }
    }
    __syncthreads();
    {
        const unsigned short* P16 = (const unsigned short*)ws + U_P;
        const int strm = t2 >> 4, e4 = t2 & 15;
        const int cc = cnt_s[half];
        float ax = 0.0f, ay = 0.0f, az = 0.0f, aw = 0.0f;
        for (int j = strm; j < cc; j += 8) {
            int o = off[half][j];
            ushort4 uu = *(const ushort4*)(P16 + o + 4 * e4);
            ax += b2f_(uu.x); ay += b2f_(uu.y); az += b2f_(uu.z); aw += b2f_(uu.w);
        }
        red4[half][strm][e4] = make_float4(ax, ay, az, aw);
    }
    __syncthreads();
    if (t2 < 16) {
        float s[4] = {0.0f, 0.0f, 0.0f, 0.0f};
#pragma unroll
        for (int s8 = 0; s8 < 8; s8++) {
            float4 r = red4[half][s8][t2];
            s[0] += r.x; s[1] += r.y; s[2] += r.z; s[3] += r.w;
        }
        int e = 4 * t2;
#pragma unroll
        for (int i = 0; i < 4; i++) {
            float v = fmaxf(s[i] + ldin(b_soc, e + i, isbf), 0.0f);
            unsigned short hi = f2bu(v);
            u[U_ACTH + n * 256 + 64 + e + i] = hi;
            u[U_ACTL + n * 256 + 64 + e + i] = f2bu(v - b2f_(hi));
        }
    }
}

// ---- K3: gates via MFMA (16 agents x 512 j per block) + pointwise + out ----
// A = act hi/lo [agent][k=256]; B = Wg[j][k] native k-contiguous. 64 blocks.
__global__ __launch_bounds__(256) void lstm_kernel(const void* __restrict__ c0,
                                                   const void* __restrict__ b_ih,
                                                   const void* __restrict__ b_hh,
                                                   const void* __restrict__ b_out,
                                                   const void* __restrict__ Wih_det,
                                                   float* __restrict__ ws,
                                                   float* __restrict__ out) {
    __shared__ float gl[16 * 516];                 // +4 pad: quad rows -> 2-way only
    __shared__ __align__(16) float hnl[16][128];
    const int tid = threadIdx.x;
    const int isbf = detect_bf16(Wih_det, tid);
    const unsigned short* u = (const unsigned short*)ws;
    const short* Ah = (const short*)(u + U_ACTH);
    const short* Al = (const short*)(u + U_ACTL);
    const short* Wg = (const short*)(u + U_WG);
    const int lane = tid & 63, wv = tid >> 6, m = lane & 15, q = lane >> 4;
    const int m0 = blockIdx.x * 16;
    floatx4 acc[8];
#pragma unroll
    for (int t = 0; t < 8; t++) acc[t] = floatx4{0.0f, 0.0f, 0.0f, 0.0f};
    for (int ks = 0; ks < 8; ks++) {
        const int ab = (m0 + m) * 256 + ks * 32 + q * 8;
        short8 ah = *(const short8*)(Ah + ab);
        short8 al = *(const short8*)(Al + ab);
#pragma unroll
        for (int t = 0; t < 8; t++) {
            const int j = (wv * 8 + t) * 16 + m;   // B col = lane&15
            short8 b = *(const short8*)(Wg + j * 256 + ks * 32 + q * 8);
            acc[t] = __builtin_amdgcn_mfma_f32_16x16x32_bf16(ah, b, acc[t], 0, 0, 0);
            acc[t] = __builtin_amdgcn_mfma_f32_16x16x32_bf16(al, b, acc[t], 0, 0, 0);
        }
    }
#pragma unroll
    for (int t = 0; t < 8; t++) {
        const int jc = (wv * 8 + t) * 16 + m;
        float bias = ldin(b_ih, jc, isbf) + ldin(b_hh, jc, isbf);
#pragma unroll
        for (int r = 0; r < 4; r++)                // D row = q*4+r = agent in tile
            gl[(q * 4 + r) * 516 + jc] = acc[t][r] + bias;
    }
    __syncthreads();
    for (int i = tid; i < 2048; i += 256) {
        int a = i >> 7, r = i & 127;
        float iv = gl[a * 516 + r],       fv = gl[a * 516 + r + 128];
        float gv = gl[a * 516 + r + 256], ov = gl[a * 516 + r + 384];
        float si = 1.0f / (1.0f + expf(-iv));
        float sf = 1.0f / (1.0f + expf(-fv));
        float so = 1.0f / (1.0f + expf(-ov));
        float cc = sf * ldin(c0, (m0 + a) * 128 + r, isbf) + si * tanhf(gv);
        hnl[a][r] = so * tanhf(cc);
    }
    __syncthreads();
    for (int i = tid; i < 2048; i += 256) {
        int a = i >> 7, j = i & 127;
        if (j < 120) {
            float acc2 = ldin(b_out, j, isbf);
            for (int r = 0; r < 128; r += 4) {
                float4 hq = *(const float4*)&hnl[a][r];
                acc2 = fmaf(hq.x, b2f_(u[U_WOUT + (r + 0) * 128 + j]), acc2);
                acc2 = fmaf(hq.y, b2f_(u[U_WOUT + (r + 1) * 128 + j]), acc2);
                acc2 = fmaf(hq.z, b2f_(u[U_WOUT + (r + 2) * 128 + j]), acc2);
                acc2 = fmaf(hq.w, b2f_(u[U_WOUT + (r + 3) * 128 + j]), acc2);
            }
            int ch = j / 20, wc = j - ch * 20;
            out[ch * 20480 + (m0 + a) * 20 + wc] = acc2;   // f32, [6][1024][20]
        }
    }
}

extern "C" void kernel_launch(void* const* d_in, const int* in_sizes, int n_in,
                              void* d_out, int out_size, void* d_ws, size_t ws_size,
                              hipStream_t stream) {
    const void* xoff  = d_in[0];
    const void* xabs  = d_in[1];
    const void* h0    = d_in[2];
    const void* c0    = d_in[3];
    const void* W_emb = d_in[4];
    const void* b_emb = d_in[5];
    const void* W_soc = d_in[6];
    const void* b_soc = d_in[7];
    const void* W_ih  = d_in[8];
    const void* W_hh  = d_in[9];
    const void* b_ih  = d_in[10];
    const void* b_hh  = d_in[11];
    const void* W_out = d_in[12];
    const void* b_out = d_in[13];
    float* ws = (float*)d_ws;
    float* out = (float*)d_out;

    prep_kernel<<<1024, 256, 0, stream>>>(xoff, h0, W_soc, W_emb, b_emb,
                                          W_ih, W_hh, W_out, ws);
    pgemm_kernel<<<dim3(64, 16), 256, 0, stream>>>(ws);
    pool_kernel<<<512, 256, 0, stream>>>(xabs, b_soc, W_ih, ws);
    lstm_kernel<<<64, 256, 0, stream>>>(c0, b_ih, b_hh, b_out, W_ih, ws, out);
}

// Round 14
// 125.848 us; speedup vs baseline: 1.9100x; 1.9100x over previous
//
#include <hip/hip_runtime.h>
#include <hip/hip_bf16.h>

#define NN_ 1024

// ws ushort-element offsets (~11.2 MB of the 256 MiB ws)
#define U_WIHT 0         // 65536: WihT[k][j] 128x512 bf16
#define U_WHHT 65536     // 65536: WhhT[k][j]
#define U_WOUT 131072    // 16384: WoutT[r][j] 128x128, j>=120 zero
#define U_SHI  147456    // 524288: W_soc hi, FRAGMENT-MAJOR: ((g*4+j)*4+q)*512 + e*8 + r
#define U_SLO  671744    // 524288: W_soc lo residual, same layout
#define U_HHI  1196032   // 131072: bf16 hi of h0 [m][h]
#define U_HLO  1327104   // 131072: bf16 lo residual
#define U_P    1458176   // 4194304: P[m][g*64+e] bf16

typedef __attribute__((ext_vector_type(8))) short short8;
typedef __attribute__((ext_vector_type(4))) float floatx4;

__device__ __forceinline__ float b2f_(unsigned short u) {
    return __uint_as_float(((unsigned)u) << 16);           // bf16 -> f32, exact
}
__device__ __forceinline__ unsigned short f2bu(float f) {  // f32 -> bf16 bits (RNE)
    __hip_bfloat16 b = __float2bfloat16(f);
    return *(unsigned short*)&b;
}
__device__ __forceinline__ float ldin(const void* p, int i, int isbf) {
    return isbf ? b2f_(((const unsigned short*)p)[i]) : ((const float*)p)[i];
}
__device__ __forceinline__ int detect_bf16(const void* Wih, int tid) {
    unsigned wv = ((const unsigned*)Wih)[tid];
    unsigned e8 = (wv >> 7) & 0xFFu;
    return (__syncthreads_count((e8 >= 96u && e8 <= 134u) ? 1 : 0) > 128) ? 1 : 0;
}

// ---- K0: weight transposes + W_soc fragment-major hi/lo split + h0 hi/lo ----
// 802816 tasks, dest-linear (writes coalesced).
__global__ __launch_bounds__(256) void prep_kernel(
        const void* __restrict__ h0,  const void* __restrict__ Wsoc,
        const void* __restrict__ Wih, const void* __restrict__ Whh,
        const void* __restrict__ Wout, float* __restrict__ ws) {
    const int tid = threadIdx.x;
    const int isbf = detect_bf16(Wih, tid);
    unsigned short* u = (unsigned short*)ws;
    int t = blockIdx.x * 256 + tid;                // 0..802815
    if (t < 65536) {                               // WihT[k*512+j]
        int k = t >> 9, j = t & 511;
        u[U_WIHT + t] = f2bu(ldin(Wih, j * 128 + k, isbf));
    } else if (t < 131072) {                       // WhhT
        int t2 = t - 65536; int k = t2 >> 9, j = t2 & 511;
        u[U_WHHT + t2] = f2bu(ldin(Whh, j * 128 + k, isbf));
    } else if (t < 147456) {                       // WoutT[r*128+j]
        int t2 = t - 131072; int r = t2 >> 7, j = t2 & 127;
        u[U_WOUT + t2] = f2bu((j < 120) ? ldin(Wout, j * 128 + r, isbf) : 0.0f);
    } else if (t < 671744) {                       // W_soc fragment-major split
        int t2 = t - 147456;
        int r = t2 & 7, e = (t2 >> 3) & 63, q = (t2 >> 9) & 3;
        int j = (t2 >> 11) & 3, g = t2 >> 13;
        float x = ldin(Wsoc, e * 8192 + g * 128 + j * 32 + q * 8 + r, isbf);
        unsigned short hi = f2bu(x);
        u[U_SHI + t2] = hi;
        u[U_SLO + t2] = f2bu(x - b2f_(hi));
    } else {                                       // h0 hi/lo
        int t2 = t - 671744;                       // 0..131071
        float x = ldin(h0, t2, isbf);
        unsigned short hi = f2bu(x);
        u[U_HHI + t2] = hi;
        u[U_HLO + t2] = f2bu(x - b2f_(hi));
    }
}

// ---- K1: P[m, g*64+e] = sum_h h0[m,h]*W_soc[e,g*128+h], hi/lo MFMA ----
// Block = 16 m-rows x 256 cols (4 waves x 4 col-tiles). B loads COALESCED via
// fragment-major Sfrag: quad reads 16 lanes x 16B contiguous.
// A: m=lane&15, k=q*8+j; D: col=lane&15, row=q*4+r (HW-verified).
__global__ __launch_bounds__(256) void pgemm_kernel(float* __restrict__ ws) {
    const unsigned short* u = (const unsigned short*)ws;
    const short* Hhi = (const short*)(u + U_HHI);
    const short* Hlo = (const short*)(u + U_HLO);
    const short* Shi = (const short*)(u + U_SHI);
    const short* Slo = (const short*)(u + U_SLO);
    unsigned short* P16 = (unsigned short*)ws + U_P;
    const int tid = threadIdx.x, lane = tid & 63, wv = tid >> 6;
    const int B_ = blockIdx.y * 64 + blockIdx.x;   // 0..1023
    const int mtile = B_ & 63, cg = B_ >> 6;
    const int m = lane & 15, q = lane >> 4;
    const int g = cg * 4 + wv;                     // wave-uniform B row-group
    const int abase = (mtile * 16 + m) * 128 + q * 8;
    short8 ah[4], al[4];
#pragma unroll
    for (int j = 0; j < 4; j++) {
        ah[j] = *(const short8*)(Hhi + abase + 32 * j);
        al[j] = *(const short8*)(Hlo + abase + 32 * j);
    }
    const int rowl = mtile * 16 + q * 4;
#pragma unroll
    for (int t = 0; t < 4; t++) {
        const int e = t * 16 + m;                  // B col within group g
        short8 bh[4], bl[4];
#pragma unroll
        for (int j = 0; j < 4; j++) {
            const int fb = ((g * 4 + j) * 4 + q) * 512 + e * 8;  // coalesced
            bh[j] = *(const short8*)(Shi + fb);
            bl[j] = *(const short8*)(Slo + fb);
        }
        floatx4 c = {0.0f, 0.0f, 0.0f, 0.0f};
#pragma unroll
        for (int j = 0; j < 4; j++) c = __builtin_amdgcn_mfma_f32_16x16x32_bf16(ah[j], bh[j], c, 0, 0, 0);
#pragma unroll
        for (int j = 0; j < 4; j++) c = __builtin_amdgcn_mfma_f32_16x16x32_bf16(ah[j], bl[j], c, 0, 0, 0);
#pragma unroll
        for (int j = 0; j < 4; j++) c = __builtin_amdgcn_mfma_f32_16x16x32_bf16(al[j], bh[j], c, 0, 0, 0);
        const int n0 = cg * 256 + wv * 64 + t * 16;
#pragma unroll
        for (int r = 0; r < 4; r++)
            P16[(rowl + r) * 4096 + n0 + m] = f2bu(c[r]);
    }
}

// ---- K2: fused pool + emb + gates + LSTM pointwise + output (2 agents/block) ----
__global__ __launch_bounds__(256) void pool_lstm_kernel(
        const void* __restrict__ xoff, const void* __restrict__ xabs,
        const void* __restrict__ h0,   const void* __restrict__ c0,
        const void* __restrict__ W_emb, const void* __restrict__ b_emb,
        const void* __restrict__ b_soc, const void* __restrict__ b_ih,
        const void* __restrict__ b_hh,  const void* __restrict__ b_out,
        const void* __restrict__ Wih_det,
        const float* __restrict__ ws, float* __restrict__ out) {
    __shared__ float xabs_s[2048];
    __shared__ int   off[2][NN_];
    __shared__ int   cnt_s[2];
    __shared__ float4 red4[2][8][16];
    __shared__ __align__(16) float xin[2][128];
    __shared__ __align__(16) float hs[2][128];
    __shared__ __align__(16) float gl[2][512];
    __shared__ __align__(16) float hnl[2][128];
    const int tid = threadIdx.x;
    const int isbf = detect_bf16(Wih_det, tid);
    const int n0 = blockIdx.x * 2;
    const unsigned short* u16 = (const unsigned short*)ws;

    for (int i = tid; i < 2048; i += 256) xabs_s[i] = ldin(xabs, i, isbf);
    if (tid < 2) cnt_s[tid] = 0;
    __syncthreads();

    const int half = tid >> 7;                     // agent 0/1 (wave-uniform)
    const int t2 = tid & 127;
    const int n = n0 + half;
    {
        float xs = xabs_s[2 * n]     - 0.2f;       // x[n] - NS/2
        float ys = xabs_s[2 * n + 1] - 0.2f;
        for (int i = t2; i < NN_; i += 128) {
            float dx = xabs_s[2 * i]     - xs;
            float dy = xabs_s[2 * i + 1] - ys;
            int cx = (int)floorf(dx / 0.4f * 8.0f);
            int cy = (int)floorf(dy / 0.4f * 8.0f);
            bool valid = (dx >= 0.0f) && (dx < 0.4f) && (dy >= 0.0f) && (dy < 0.4f)
                      && (cx >= 0) && (cx < 8) && (cy >= 0) && (cy < 8) && (i != n);
            if (valid) {
                int idx = atomicAdd(&cnt_s[half], 1);
                off[half][idx] = i * 4096 + ((cy * 8 + cx) << 6);
            }
        }
    }
    __syncthreads();
    {   // branch-free gathers: 8 streams x 16 e4-lanes per agent
        const unsigned short* P16 = (const unsigned short*)ws + U_P;
        const int strm = t2 >> 4, e4 = t2 & 15;
        const int cc = cnt_s[half];
        float ax = 0.0f, ay = 0.0f, az = 0.0f, aw = 0.0f;
        for (int j = strm; j < cc; j += 8) {
            int o = off[half][j];
            ushort4 uu = *(const ushort4*)(P16 + o + 4 * e4);
            ax += b2f_(uu.x); ay += b2f_(uu.y); az += b2f_(uu.z); aw += b2f_(uu.w);
        }
        red4[half][strm][e4] = make_float4(ax, ay, az, aw);
    }
    __syncthreads();
    if (t2 < 16) {
        float4 s = make_float4(0.0f, 0.0f, 0.0f, 0.0f);
#pragma unroll
        for (int s8 = 0; s8 < 8; s8++) {
            float4 r = red4[half][s8][t2];
            s.x += r.x; s.y += r.y; s.z += r.z; s.w += r.w;
        }
        int e = 4 * t2;
        xin[half][64 + e]     = fmaxf(s.x + ldin(b_soc, e,     isbf), 0.0f);
        xin[half][64 + e + 1] = fmaxf(s.y + ldin(b_soc, e + 1, isbf), 0.0f);
        xin[half][64 + e + 2] = fmaxf(s.z + ldin(b_soc, e + 2, isbf), 0.0f);
        xin[half][64 + e + 3] = fmaxf(s.w + ldin(b_soc, e + 3, isbf), 0.0f);
    }
    if (t2 < 64) {
        int e = t2;
        float v = fmaf(ldin(xoff, 2 * n, isbf),     ldin(W_emb, 2 * e, isbf),
                  fmaf(ldin(xoff, 2 * n + 1, isbf), ldin(W_emb, 2 * e + 1, isbf),
                       ldin(b_emb, e, isbf)));
        xin[half][e] = fmaxf(v, 0.0f);
    }
    hs[half][t2] = ldin(h0, n * 128 + t2, isbf);
    __syncthreads();
    {   // gates via coalesced bf16 WT[k][j]
        const int j0 = 2 * tid, j1 = 2 * tid + 1;
        float ax[2] = {0, 0}, ay[2] = {0, 0};
        for (int k = 0; k < 128; k += 4) {
            union { float4 v; float f[4]; } xu[2], hu[2];
#pragma unroll
            for (int nn = 0; nn < 2; nn++) {
                xu[nn].v = *(const float4*)&xin[nn][k];
                hu[nn].v = *(const float4*)&hs[nn][k];
            }
#pragma unroll
            for (int kk = 0; kk < 4; kk++) {
                ushort2 wi = *(const ushort2*)(u16 + U_WIHT + (k + kk) * 512 + j0);
                ushort2 wh = *(const ushort2*)(u16 + U_WHHT + (k + kk) * 512 + j0);
                float wix = b2f_(wi.x), wiy = b2f_(wi.y);
                float whx = b2f_(wh.x), why = b2f_(wh.y);
#pragma unroll
                for (int nn = 0; nn < 2; nn++) {
                    float xk = xu[nn].f[kk], hk = hu[nn].f[kk];
                    ax[nn] = fmaf(xk, wix, ax[nn]); ax[nn] = fmaf(hk, whx, ax[nn]);
                    ay[nn] = fmaf(xk, wiy, ay[nn]); ay[nn] = fmaf(hk, why, ay[nn]);
                }
            }
        }
        float bb0 = ldin(b_ih, j0, isbf) + ldin(b_hh, j0, isbf);
        float bb1 = ldin(b_ih, j1, isbf) + ldin(b_hh, j1, isbf);
#pragma unroll
        for (int nn = 0; nn < 2; nn++) {
            gl[nn][j0] = ax[nn] + bb0;
            gl[nn][j1] = ay[nn] + bb1;
        }
    }
    __syncthreads();
    {   // LSTM pointwise
        int r = t2;
        float iv = gl[half][r], fv = gl[half][r + 128];
        float gv = gl[half][r + 256], ov = gl[half][r + 384];
        float si = 1.0f / (1.0f + expf(-iv));
        float sf = 1.0f / (1.0f + expf(-fv));
        float so = 1.0f / (1.0f + expf(-ov));
        float cc = sf * ldin(c0, n * 128 + r, isbf) + si * tanhf(gv);
        hnl[half][r] = so * tanhf(cc);
    }
    __syncthreads();
    {   // output projection, d_out = [6][1024][20] f32
        int j = t2;
        if (j < 120) {
            float acc = ldin(b_out, j, isbf);
            for (int r = 0; r < 128; r += 4) {
                float4 hq = *(const float4*)&hnl[half][r];
                acc = fmaf(hq.x, b2f_(u16[U_WOUT + (r + 0) * 128 + j]), acc);
                acc = fmaf(hq.y, b2f_(u16[U_WOUT + (r + 1) * 128 + j]), acc);
                acc = fmaf(hq.z, b2f_(u16[U_WOUT + (r + 2) * 128 + j]), acc);
                acc = fmaf(hq.w, b2f_(u16[U_WOUT + (r + 3) * 128 + j]), acc);
            }
            int ch = j / 20, wc = j - ch * 20;
            out[ch * 20480 + n * 20 + wc] = acc;
        }
    }
}

extern "C" void kernel_launch(void* const* d_in, const int* in_sizes, int n_in,
                              void* d_out, int out_size, void* d_ws, size_t ws_size,
                              hipStream_t stream) {
    const void* xoff  = d_in[0];
    const void* xabs  = d_in[1];
    const void* h0    = d_in[2];
    const void* c0    = d_in[3];
    const void* W_emb = d_in[4];
    const void* b_emb = d_in[5];
    const void* W_soc = d_in[6];
    const void* b_soc = d_in[7];
    const void* W_ih  = d_in[8];
    const void* W_hh  = d_in[9];
    const void* b_ih  = d_in[10];
    const void* b_hh  = d_in[11];
    const void* W_out = d_in[12];
    const void* b_out = d_in[13];
    float* ws = (float*)d_ws;
    float* out = (float*)d_out;

    prep_kernel<<<3136, 256, 0, stream>>>(h0, W_soc, W_ih, W_hh, W_out, ws);
    pgemm_kernel<<<dim3(64, 16), 256, 0, stream>>>(ws);
    pool_lstm_kernel<<<512, 256, 0, stream>>>(xoff, xabs, h0, c0, W_emb, b_emb,
                                              b_soc, b_ih, b_hh, b_out, W_ih, ws, out);
}

// Round 15
// 125.160 us; speedup vs baseline: 1.9205x; 1.0055x over previous
//
#include <hip/hip_runtime.h>
#include <hip/hip_bf16.h>

#define NN_ 1024

// ws ushort-element offsets (~14 MB of the 256 MiB ws)
#define U_WGF  0         // 131072: Wg fragment-major: ((jt*8+kb)*4+q)*128 + jl*8 + r
                         //         value = Wg[j=jt*16+jl][k=kb*32+q*8+r]; k<128 Wih else Whh
#define U_WOUT 131072    // 16384:  WoutT[r][j] 128x128, j>=120 zero
#define U_SHI  147456    // 524288: W_soc hi, fragment-major ((g*4+j)*4+q)*512 + e*8 + r
#define U_SLO  671744    // 524288: lo residual
#define U_ACTH 1196032   // 262144: act_hi[n][k] 1024x256 (0-63 emb, 64-127 pool, 128-255 h0)
#define U_ACTL 1458176   // 262144: act_lo residual
#define U_P    1720320   // 4194304: P[m][g*64+e] bf16
#define F_GL   2957312   // FLOAT offset: gl[n][j] 1024x512 f32

typedef __attribute__((ext_vector_type(8))) short short8;
typedef __attribute__((ext_vector_type(4))) float floatx4;

__device__ __forceinline__ float b2f_(unsigned short u) {
    return __uint_as_float(((unsigned)u) << 16);           // bf16 -> f32, exact
}
__device__ __forceinline__ unsigned short f2bu(float f) {  // f32 -> bf16 bits (RNE)
    __hip_bfloat16 b = __float2bfloat16(f);
    return *(unsigned short*)&b;
}
__device__ __forceinline__ float ldin(const void* p, int i, int isbf) {
    return isbf ? b2f_(((const unsigned short*)p)[i]) : ((const float*)p)[i];
}
__device__ __forceinline__ int detect_bf16(const void* Wih, int tid) {
    unsigned wv = ((const unsigned*)Wih)[tid];
    unsigned e8 = (wv >> 7) & 0xFFu;
    return (__syncthreads_count((e8 >= 96u && e8 <= 134u) ? 1 : 0) > 128) ? 1 : 0;
}

// ---- K0: all one-time conversions (868352 tasks, dest-linear writes) ----
__global__ __launch_bounds__(256) void prep_kernel(
        const void* __restrict__ xoff, const void* __restrict__ h0,
        const void* __restrict__ Wsoc, const void* __restrict__ Wemb,
        const void* __restrict__ bemb, const void* __restrict__ Wih,
        const void* __restrict__ Whh,  const void* __restrict__ Wout,
        float* __restrict__ ws) {
    const int tid = threadIdx.x;
    const int isbf = detect_bf16(Wih, tid);
    unsigned short* u = (unsigned short*)ws;
    int t = blockIdx.x * 256 + tid;
    if (t < 131072) {                              // Wg fragment-major (hi only)
        int r = t & 7, jl = (t >> 3) & 15, q = (t >> 7) & 3;
        int kb = (t >> 9) & 7, jt = t >> 12;
        int j = jt * 16 + jl, k = kb * 32 + q * 8 + r;
        float v = (k < 128) ? ldin(Wih, j * 128 + k, isbf)
                            : ldin(Whh, j * 128 + (k - 128), isbf);
        u[U_WGF + t] = f2bu(v);
    } else if (t < 147456) {                       // WoutT[r*128+j]
        int t2 = t - 131072; int r = t2 >> 7, j = t2 & 127;
        u[U_WOUT + t2] = f2bu((j < 120) ? ldin(Wout, j * 128 + r, isbf) : 0.0f);
    } else if (t < 671744) {                       // W_soc fragment-major hi/lo
        int t2 = t - 147456;
        int r = t2 & 7, e = (t2 >> 3) & 63, q = (t2 >> 9) & 3;
        int j = (t2 >> 11) & 3, g = t2 >> 13;
        float x = ldin(Wsoc, e * 8192 + g * 128 + j * 32 + q * 8 + r, isbf);
        unsigned short hi = f2bu(x);
        u[U_SHI + t2] = hi;
        u[U_SLO + t2] = f2bu(x - b2f_(hi));
    } else if (t < 802816) {                       // h0 -> act k=128..255 hi/lo
        int t2 = t - 671744; int n = t2 >> 7, k = t2 & 127;
        float x = ldin(h0, t2, isbf);
        unsigned short hi = f2bu(x);
        u[U_ACTH + n * 256 + 128 + k] = hi;
        u[U_ACTL + n * 256 + 128 + k] = f2bu(x - b2f_(hi));
    } else {                                       // emb -> act k=0..63 hi/lo
        int t2 = t - 802816; int n = t2 >> 6, e = t2 & 63;
        float v = fmaf(ldin(xoff, 2 * n, isbf),     ldin(Wemb, 2 * e, isbf),
                  fmaf(ldin(xoff, 2 * n + 1, isbf), ldin(Wemb, 2 * e + 1, isbf),
                       ldin(bemb, e, isbf)));
        v = fmaxf(v, 0.0f);
        unsigned short hi = f2bu(v);
        u[U_ACTH + n * 256 + e] = hi;
        u[U_ACTL + n * 256 + e] = f2bu(v - b2f_(hi));
    }
}

// ---- K1: P = h0 @ W_socT via hi/lo MFMA. 2048 blocks (2 col-tiles each) ----
__global__ __launch_bounds__(256) void pgemm_kernel(float* __restrict__ ws) {
    const unsigned short* u = (const unsigned short*)ws;
    const short* Ah  = (const short*)(u + U_ACTH);
    const short* Al  = (const short*)(u + U_ACTL);
    const short* Shi = (const short*)(u + U_SHI);
    const short* Slo = (const short*)(u + U_SLO);
    unsigned short* P16 = (unsigned short*)ws + U_P;
    const int tid = threadIdx.x, lane = tid & 63, wv = tid >> 6;
    const int B_ = blockIdx.y * 64 + blockIdx.x;   // 0..2047
    const int mtile = B_ & 63, rest = B_ >> 6;     // rest 0..31
    const int cg = rest >> 1, thalf = rest & 1;
    const int m = lane & 15, q = lane >> 4;
    const int g = cg * 4 + wv;                     // wave-uniform B row-group
    const int abase = (mtile * 16 + m) * 256 + 128 + q * 8;
    short8 ah[4], al[4];
#pragma unroll
    for (int j = 0; j < 4; j++) {
        ah[j] = *(const short8*)(Ah + abase + 32 * j);
        al[j] = *(const short8*)(Al + abase + 32 * j);
    }
    const int rowl = mtile * 16 + q * 4;
#pragma unroll
    for (int tt = 0; tt < 2; tt++) {
        const int t = thalf * 2 + tt;
        const int e = t * 16 + m;
        short8 bh[4], bl[4];
#pragma unroll
        for (int j = 0; j < 4; j++) {
            const int fb = ((g * 4 + j) * 4 + q) * 512 + e * 8;  // coalesced
            bh[j] = *(const short8*)(Shi + fb);
            bl[j] = *(const short8*)(Slo + fb);
        }
        floatx4 c = {0.0f, 0.0f, 0.0f, 0.0f};
#pragma unroll
        for (int j = 0; j < 4; j++) c = __builtin_amdgcn_mfma_f32_16x16x32_bf16(ah[j], bh[j], c, 0, 0, 0);
#pragma unroll
        for (int j = 0; j < 4; j++) c = __builtin_amdgcn_mfma_f32_16x16x32_bf16(ah[j], bl[j], c, 0, 0, 0);
#pragma unroll
        for (int j = 0; j < 4; j++) c = __builtin_amdgcn_mfma_f32_16x16x32_bf16(al[j], bh[j], c, 0, 0, 0);
        const int n0 = cg * 256 + wv * 64 + t * 16;
#pragma unroll
        for (int r = 0; r < 4; r++)                // D: col=lane&15, row=q*4+r
            P16[(rowl + r) * 4096 + n0 + m] = f2bu(c[r]);
    }
}

// ---- K2: pool gather, 1 agent/block (1024 blocks); writes act k=64..127 ----
__global__ __launch_bounds__(256) void pool_kernel(const void* __restrict__ xabs,
                                                   const void* __restrict__ b_soc,
                                                   const void* __restrict__ Wih_det,
                                                   float* __restrict__ ws) {
    __shared__ float xabs_s[2048];
    __shared__ int   off[NN_];
    __shared__ int   cnt_s;
    __shared__ float4 red4[16][16];
    const int tid = threadIdx.x;
    const int isbf = detect_bf16(Wih_det, tid);
    const int n = blockIdx.x;
    unsigned short* u = (unsigned short*)ws;

    for (int i = tid; i < 2048; i += 256) xabs_s[i] = ldin(xabs, i, isbf);
    if (tid == 0) cnt_s = 0;
    __syncthreads();
    {
        float xs = xabs_s[2 * n]     - 0.2f;       // x[n] - NS/2
        float ys = xabs_s[2 * n + 1] - 0.2f;
        for (int i = tid; i < NN_; i += 256) {
            float dx = xabs_s[2 * i]     - xs;
            float dy = xabs_s[2 * i + 1] - ys;
            int cx = (int)floorf(dx / 0.4f * 8.0f);
            int cy = (int)floorf(dy / 0.4f * 8.0f);
            bool valid = (dx >= 0.0f) && (dx < 0.4f) && (dy >= 0.0f) && (dy < 0.4f)
                      && (cx >= 0) && (cx < 8) && (cy >= 0) && (cy < 8) && (i != n);
            if (valid) {
                int idx = atomicAdd(&cnt_s, 1);
                off[idx] = i * 4096 + ((cy * 8 + cx) << 6);
            }
        }
    }
    __syncthreads();
    {   // branch-free gathers: 16 streams x 16 e4-lanes
        const unsigned short* P16 = (const unsigned short*)ws + U_P;
        const int strm = tid >> 4, e4 = tid & 15;
        const int cc = cnt_s;
        float ax = 0.0f, ay = 0.0f, az = 0.0f, aw = 0.0f;
        for (int j = strm; j < cc; j += 16) {
            int o = off[j];
            ushort4 uu = *(const ushort4*)(P16 + o + 4 * e4);
            ax += b2f_(uu.x); ay += b2f_(uu.y); az += b2f_(uu.z); aw += b2f_(uu.w);
        }
        red4[strm][e4] = make_float4(ax, ay, az, aw);
    }
    __syncthreads();
    if (tid < 16) {
        float s[4] = {0.0f, 0.0f, 0.0f, 0.0f};
#pragma unroll
        for (int s16 = 0; s16 < 16; s16++) {
            float4 r = red4[s16][tid];
            s[0] += r.x; s[1] += r.y; s[2] += r.z; s[3] += r.w;
        }
        int e = 4 * tid;
#pragma unroll
        for (int i = 0; i < 4; i++) {
            float v = fmaxf(s[i] + ldin(b_soc, e + i, isbf), 0.0f);
            unsigned short hi = f2bu(v);
            u[U_ACTH + n * 256 + 64 + e + i] = hi;
            u[U_ACTL + n * 256 + 64 + e + i] = f2bu(v - b2f_(hi));
        }
    }
}

// ---- K3: gates = act @ WgT via MFMA (M=1024,N=512,K=256). 512 blocks, no LDS.
// Wave = 16 agents x 16 j, 8 K-blocks x (hi,lo) = 16 MFMA. B coalesced (WgF). ----
__global__ __launch_bounds__(256) void gates_kernel(const void* __restrict__ b_ih,
                                                    const void* __restrict__ b_hh,
                                                    const void* __restrict__ Wih_det,
                                                    float* __restrict__ ws) {
    const int tid = threadIdx.x;
    const int isbf = detect_bf16(Wih_det, tid);
    const unsigned short* u = (const unsigned short*)ws;
    const short* Ah = (const short*)(u + U_ACTH);
    const short* Al = (const short*)(u + U_ACTL);
    const short* Wg = (const short*)(u + U_WGF);
    float* gl = ws + F_GL;
    const int lane = tid & 63, wv = tid >> 6, m = lane & 15, q = lane >> 4;
    const int m0 = blockIdx.x * 16;
    const int jt = blockIdx.y * 4 + wv;            // 0..31 (j-tile of 16)
    floatx4 acc = {0.0f, 0.0f, 0.0f, 0.0f};
#pragma unroll
    for (int kb = 0; kb < 8; kb++) {
        const int ab = (m0 + m) * 256 + kb * 32 + q * 8;
        short8 ah = *(const short8*)(Ah + ab);
        short8 al = *(const short8*)(Al + ab);
        short8 b  = *(const short8*)(Wg + (jt * 8 + kb) * 512 + q * 128 + m * 8);
        acc = __builtin_amdgcn_mfma_f32_16x16x32_bf16(ah, b, acc, 0, 0, 0);
        acc = __builtin_amdgcn_mfma_f32_16x16x32_bf16(al, b, acc, 0, 0, 0);
    }
    const int j = jt * 16 + m;                     // D col = lane&15
    const float bias = ldin(b_ih, j, isbf) + ldin(b_hh, j, isbf);
#pragma unroll
    for (int r = 0; r < 4; r++)                    // D row = q*4+r = agent local
        gl[(m0 + q * 4 + r) * 512 + j] = acc[r] + bias;
}

// ---- K4: LSTM pointwise + output projection (2 agents/block, 512 blocks) ----
__global__ __launch_bounds__(256) void pwout_kernel(const void* __restrict__ c0,
                                                    const void* __restrict__ b_out,
                                                    const void* __restrict__ Wih_det,
                                                    const float* __restrict__ ws,
                                                    float* __restrict__ out) {
    __shared__ __align__(16) float hnl[2][128];
    const int tid = threadIdx.x;
    const int isbf = detect_bf16(Wih_det, tid);
    const int n0 = blockIdx.x * 2;
    const unsigned short* u = (const unsigned short*)ws;
    const float* gl = ws + F_GL;
    const int half = tid >> 7, t2 = tid & 127;
    const int n = n0 + half;
    {
        int r = t2;
        float iv = gl[n * 512 + r],       fv = gl[n * 512 + r + 128];
        float gv = gl[n * 512 + r + 256], ov = gl[n * 512 + r + 384];
        float si = 1.0f / (1.0f + expf(-iv));
        float sf = 1.0f / (1.0f + expf(-fv));
        float so = 1.0f / (1.0f + expf(-ov));
        float cc = sf * ldin(c0, n * 128 + r, isbf) + si * tanhf(gv);
        hnl[half][r] = so * tanhf(cc);
    }
    __syncthreads();
    {
        int j = t2;
        if (j < 120) {
            float acc = ldin(b_out, j, isbf);
            for (int r = 0; r < 128; r += 4) {
                float4 hq = *(const float4*)&hnl[half][r];
                acc = fmaf(hq.x, b2f_(u[U_WOUT + (r + 0) * 128 + j]), acc);
                acc = fmaf(hq.y, b2f_(u[U_WOUT + (r + 1) * 128 + j]), acc);
                acc = fmaf(hq.z, b2f_(u[U_WOUT + (r + 2) * 128 + j]), acc);
                acc = fmaf(hq.w, b2f_(u[U_WOUT + (r + 3) * 128 + j]), acc);
            }
            int ch = j / 20, wc = j - ch * 20;
            out[ch * 20480 + n * 20 + wc] = acc;   // f32, [6][1024][20]
        }
    }
}

extern "C" void kernel_launch(void* const* d_in, const int* in_sizes, int n_in,
                              void* d_out, int out_size, void* d_ws, size_t ws_size,
                              hipStream_t stream) {
    const void* xoff  = d_in[0];
    const void* xabs  = d_in[1];
    const void* h0    = d_in[2];
    const void* c0    = d_in[3];
    const void* W_emb = d_in[4];
    const void* b_emb = d_in[5];
    const void* W_soc = d_in[6];
    const void* b_soc = d_in[7];
    const void* W_ih  = d_in[8];
    const void* W_hh  = d_in[9];
    const void* b_ih  = d_in[10];
    const void* b_hh  = d_in[11];
    const void* W_out = d_in[12];
    const void* b_out = d_in[13];
    float* ws = (float*)d_ws;
    float* out = (float*)d_out;

    prep_kernel<<<3392, 256, 0, stream>>>(xoff, h0, W_soc, W_emb, b_emb,
                                          W_ih, W_hh, W_out, ws);
    pgemm_kernel<<<dim3(64, 32), 256, 0, stream>>>(ws);
    pool_kernel<<<1024, 256, 0, stream>>>(xabs, b_soc, W_ih, ws);
    gates_kernel<<<dim3(64, 8), 256, 0, stream>>>(b_ih, b_hh, W_ih, ws);
    pwout_kernel<<<512, 256, 0, stream>>>(c0, b_out, W_ih, ws, out);
}